// Round 6
// baseline (800.673 us; speedup 1.0000x reference)
//
#include <hip/hip_runtime.h>
#include <hip/hip_fp16.h>
#include <math.h>

#define N_ENT  150000
#define N_USR  60000
#define CDIM   64
#define NE     1000000
#define NNZV   1000000
#define NREL9  9                        // weight rows incl. np-wrap row 8
#define E9OFF  (N_ENT * NREL9)          // 1,350,000 per-(head,rt) counters
#define NTOT2  (E9OFF + N_ENT + N_USR)  // 1,560,000 total segment counters
#define TOTAL_ITEMS (NE + 2 * NNZV)     // 3,000,000 (scan sentinel)
#define SCAN_B2 (((NTOT2 + 1) + 1023) / 1024)  // 1524 scan blocks

#define NXCD   8
#define H_PER  (N_ENT / NXCD)           // 18750 heads/cols per role
#define R_PER  (N_USR / NXCD)           // 7500 rows per role
#define EPB    2048                     // edges per chunk
#define NCHUNK ((NE + EPB - 1) / EPB)   // 489

#define EG (N_ENT / 4)                  // 37500 entity blocks (4 waves each)
#define UG (N_USR / 4)                  // 15000 user blocks

// ---- DPP wave reductions (VALU pipe, no LDS) ----------------------------
template <int CTRL>
__device__ __forceinline__ float dpp_addf(float v) {
    int iv = __float_as_int(v);
    int x = __builtin_amdgcn_update_dpp(iv, iv, CTRL, 0xF, 0xF, true);
    return v + __int_as_float(x);
}
template <int CTRL>
__device__ __forceinline__ float dpp_maxf(float v) {
    int iv = __float_as_int(v);
    int x = __builtin_amdgcn_update_dpp(iv, iv, CTRL, 0xF, 0xF, true);
    return fmaxf(v, __int_as_float(x));
}
__device__ __forceinline__ float wave_sum(float v) {
    v = dpp_addf<0x111>(v);   // row_shr:1
    v = dpp_addf<0x112>(v);   // row_shr:2
    v = dpp_addf<0x114>(v);   // row_shr:4
    v = dpp_addf<0x118>(v);   // row_shr:8
    v = dpp_addf<0x142>(v);   // row_bcast:15
    v = dpp_addf<0x143>(v);   // row_bcast:31
    return __int_as_float(__builtin_amdgcn_readlane(__float_as_int(v), 63));
}
__device__ __forceinline__ float wave_max(float v) {
    v = dpp_maxf<0x111>(v);
    v = dpp_maxf<0x112>(v);
    v = dpp_maxf<0x114>(v);
    v = dpp_maxf<0x118>(v);
    v = dpp_maxf<0x142>(v);
    v = dpp_maxf<0x143>(v);
    return __int_as_float(__builtin_amdgcn_readlane(__float_as_int(v), 63));
}

__device__ __forceinline__ int   bcast_i(int v, int l)   { return __builtin_amdgcn_readlane(v, l); }
__device__ __forceinline__ float bcast_f(float v, int l) { return __int_as_float(__builtin_amdgcn_readlane(__float_as_int(v), l)); }

// Block-wide exclusive scan (blockDim multiple of 64, <=1024). lds: >=16 ints.
__device__ __forceinline__ int block_excl_scan(int v, int* lds) {
    int lane = threadIdx.x & 63, wid = threadIdx.x >> 6;
    int incl = v;
#pragma unroll
    for (int o = 1; o < 64; o <<= 1) {
        int t = __shfl_up(incl, o, 64);
        if (lane >= o) incl += t;
    }
    if (lane == 63) lds[wid] = incl;
    __syncthreads();
    int nw = blockDim.x >> 6;
    if ((int)threadIdx.x < nw) {
        int s = lds[threadIdx.x];
        int si = s;
        for (int o = 1; o < nw; o <<= 1) {
            int t = __shfl_up(si, o, 64);
            if ((int)threadIdx.x >= o) si += t;
        }
        lds[threadIdx.x] = si - s;  // exclusive offset for this wave
    }
    __syncthreads();
    return incl - v + lds[wid];
}

__global__ __launch_bounds__(256) void k_zero(int* __restrict__ p, int n) {
    int i = blockIdx.x * 256 + threadIdx.x;
    if (i < n) p[i] = 0;
}

// fp32 -> fp16 table conversion (half2-vectorized), n2 = element-pairs.
__global__ __launch_bounds__(256) void k_cvt(
    const float* __restrict__ src, __half* __restrict__ dst, int n2)
{
    int i = blockIdx.x * 256 + threadIdx.x;
    if (i >= n2) return;
    float2 v = ((const float2*)src)[i];
    ((__half2*)dst)[i] = __floats2half2_rn(v.x, v.y);
}

// ---- CSR build: histogram -> scan(start,cursor) -> scatter ---------------
// Entity edges use per-(head,rt) counters so segments come out rt-SORTED:
// enables the run-folded gather in k_hop (1 FMA + 1 VMEM per edge).

__global__ __launch_bounds__(256) void k_hist(
    const int* __restrict__ head, const int* __restrict__ etype,
    const int* __restrict__ cols, const int* __restrict__ rows,
    int* __restrict__ cnt)
{
    int i = blockIdx.x * 256 + threadIdx.x;
    if (i >= NE) return;
    int rt = etype[i] - 1;
    if (rt < 0) rt = 8;                  // weight[-1] -> row 8 (np wrap)
    atomicAdd(cnt + head[i] * NREL9 + rt, 1);
    atomicAdd(cnt + E9OFF + cols[i], 1);
    atomicAdd(cnt + E9OFF + N_ENT + rows[i], 1);
}

__global__ __launch_bounds__(1024) void k_bsum(
    const int* __restrict__ cnt, int* __restrict__ bsum)
{
    __shared__ int lds[16];
    int i = blockIdx.x * 1024 + threadIdx.x;
    float v = (i < NTOT2) ? (float)cnt[i] : 0.f;
    float s = wave_sum(v);                 // exact: block total <= 3M < 2^24
    int lane = threadIdx.x & 63, wid = threadIdx.x >> 6;
    if (lane == 0) lds[wid] = (int)s;
    __syncthreads();
    if (threadIdx.x == 0) {
        int t = 0;
        for (int k = 0; k < 16; ++k) t += lds[k];
        bsum[blockIdx.x] = t;
    }
}

// Exclusive-scan 1524 block sums: 2 entries per thread, 1024 threads.
__global__ __launch_bounds__(1024) void k_scan_small(int* __restrict__ bsum)
{
    __shared__ int lds[16];
    int t = threadIdx.x;
    int i0 = 2 * t, i1 = 2 * t + 1;
    int a = (i0 < SCAN_B2) ? bsum[i0] : 0;
    int b = (i1 < SCAN_B2) ? bsum[i1] : 0;
    int e = block_excl_scan(a + b, lds);
    if (i0 < SCAN_B2) bsum[i0] = e;
    if (i1 < SCAN_B2) bsum[i1] = e + a;
}

// start[i] = exclusive prefix (immutable); start[NTOT2] = sentinel.
__global__ __launch_bounds__(1024) void k_scan_apply(
    const int* __restrict__ cnt, const int* __restrict__ bsum,
    int* __restrict__ start, int* __restrict__ cursor)
{
    __shared__ int lds[16];
    int i = blockIdx.x * 1024 + threadIdx.x;
    int v = (i < NTOT2) ? cnt[i] : 0;
    int e = block_excl_scan(v, lds) + bsum[blockIdx.x];
    if (i < NTOT2) { start[i] = e; cursor[i] = e; }
    else if (i == NTOT2) { start[i] = TOTAL_ITEMS; }
}

// Scatter payloads into segment-sorted arrays. XCD-localized (R0): role r
// only performs writes whose key falls in its eighth of segment space.
__global__ __launch_bounds__(256) void k_scatter(
    const int* __restrict__ head, const int* __restrict__ tail,
    const int* __restrict__ etype,
    const int* __restrict__ rows, const int* __restrict__ cols,
    const float* __restrict__ vals,
    int* __restrict__ cursor,
    int* __restrict__ pk_h,                  // tail | rt<<18, rt-sorted by head
    int2* __restrict__ rc,                   // (row, valbits) sorted by col
    int2* __restrict__ cv)                   // (col, valbits) sorted by row
{
    int role  = blockIdx.x & (NXCD - 1);
    int chunk = blockIdx.x >> 3;
    int h0 = role * H_PER, h1 = h0 + H_PER;  // head/col range for this role
    int r0 = role * R_PER, r1 = r0 + R_PER;  // row range for this role
    int base = chunk * EPB;
    int end  = min(base + EPB, NE);
    for (int i = base + (int)threadIdx.x; i < end; i += 256) {
        int h = head[i];
        int c = cols[i];
        int r = rows[i];
        if (h >= h0 && h < h1) {
            int rt = etype[i] - 1;
            if (rt < 0) rt = 8;              // weight[-1] -> row 8 (np wrap)
            int p = atomicAdd(cursor + h * NREL9 + rt, 1);
            if ((unsigned)p < (unsigned)NE) pk_h[p] = tail[i] | (rt << 18);
        }
        if (c >= h0 && c < h1) {
            int vb = __float_as_int(vals[i]);
            int p = atomicAdd(cursor + E9OFF + c, 1) - NE;
            if ((unsigned)p < (unsigned)NNZV) rc[p] = make_int2(r, vb);
        }
        if (r >= r0 && r < r1) {
            int vb = __float_as_int(vals[i]);
            int p = atomicAdd(cursor + E9OFF + N_ENT + r, 1) - 2 * NE;
            if ((unsigned)p < (unsigned)NNZV) cv[p] = make_int2(c, vb);
        }
    }
}

// ---- Fused hop-1 prep: ent fp32 -> fp16 table AND sq table (one pass) ----
__global__ __launch_bounds__(256) void k_prep_ent(
    const float* __restrict__ ent, const float* __restrict__ wt,
    __half* __restrict__ ent16, float* __restrict__ sq)
{
    int e = (blockIdx.x * 256 + threadIdx.x) >> 6;
    int lane = threadIdx.x & 63;
    if (e >= N_ENT) return;
    float own = ent[(e << 6) + lane];
    ent16[(e << 6) + lane] = __float2half(own);
    float o2 = own * own;
    float mine = 0.f;
#pragma unroll
    for (int rt = 0; rt < NREL9; ++rt) {
        float r = wt[(rt << 6) + lane];
        float s = wave_sum(o2 * r * r);
        if (lane == rt) mine = s;
    }
    if (lane < NREL9) sq[e * NREL9 + lane] = mine;
}

// ---- Fused per-hop kernel: blocks [0,EG) = entity role, rest = user. ----
// Entity gather is run-folded over rt (segments are rt-sorted): per edge
// racc += wk*t (1 fma_mix + 1 gather); wt[rt] applied once per run flush.
template <bool FIRST, bool LAST>
__global__ __launch_bounds__(256) void k_hop(
    const __half* __restrict__ ent16_cur, const __half* __restrict__ usr16_cur,
    const float* __restrict__ ent_res_base, const float* __restrict__ usr_res_base,
    const float* __restrict__ wt, const int* __restrict__ start,
    const int* __restrict__ pk_h, const float* __restrict__ sq_in,
    const int2* __restrict__ rc, const int2* __restrict__ cv,
    __half* __restrict__ ent16_next, __half* __restrict__ usr16_next,
    float* __restrict__ sq_out,
    float* __restrict__ out_ent, float* __restrict__ out_usr)
{
    int lane = threadIdx.x & 63;
    int b = blockIdx.x;

    if (b < EG) {
        // ================= entity role: one wave per entity ==============
        int e = (b * 256 + (int)threadIdx.x) >> 6;
        const int* startp = start + e * NREL9;

        int s1 = min(startp[NREL9], NE);
        int s0 = min(startp[0], s1);
        float m = 0.f, l = 0.f, acc = 0.f;    // att >= 0 so m=0 init exact
        float racc = 0.f, wv = 0.f;           // run accumulator / run weight
        int r_cur = -1, rend = s0;            // first edge triggers advance
        for (int base = s0; base < s1; base += 64) {
            int j = base + lane;
            int cnt = min(64, s1 - base);
            int pk = 0; float att = 0.f;
            if (j < s1) {                      // coalesced descriptor load
                pk = pk_h[j];
                int t = pk & 0x3FFFF, rt = (pk >> 18) & 15;
                att = sq_in[e * NREL9 + rt] * sq_in[t * NREL9 + rt];
            }
            float mn = fmaxf(m, wave_max(att));
            float scale = __expf(m - mn);      // first chunk multiplies zeros
            float p = (j < s1) ? __expf(att - mn) : 0.f;
            l = l * scale + wave_sum(p);
            acc *= scale;
            racc *= scale;                     // run partial rescales too
            m = mn;
            int k = 0;
            for (; k + 4 <= cnt; k += 4) {     // batch 4 gathers in flight
                int p0 = bcast_i(pk, k + 0), p1 = bcast_i(pk, k + 1);
                int p2 = bcast_i(pk, k + 2), p3 = bcast_i(pk, k + 3);
                float t0 = __half2float(ent16_cur[((p0 & 0x3FFFF) << 6) + lane]);
                float t1 = __half2float(ent16_cur[((p1 & 0x3FFFF) << 6) + lane]);
                float t2 = __half2float(ent16_cur[((p2 & 0x3FFFF) << 6) + lane]);
                float t3 = __half2float(ent16_cur[((p3 & 0x3FFFF) << 6) + lane]);
                float w0 = bcast_f(p, k + 0), w1 = bcast_f(p, k + 1);
                float w2 = bcast_f(p, k + 2), w3 = bcast_f(p, k + 3);
#pragma unroll
                for (int q = 0; q < 4; ++q) {
                    int ja = base + k + q;     // uniform run-boundary check
                    if (ja >= rend) {
                        acc = fmaf(wv, racc, acc); racc = 0.f;
                        do { ++r_cur; rend = startp[r_cur + 1]; } while (ja >= rend);
                        wv = wt[(r_cur << 6) + lane];
                    }
                    float tq = (q == 0) ? t0 : (q == 1) ? t1 : (q == 2) ? t2 : t3;
                    float wq = (q == 0) ? w0 : (q == 1) ? w1 : (q == 2) ? w2 : w3;
                    racc = fmaf(wq, tq, racc);
                }
            }
            for (; k < cnt; ++k) {
                int pkk = bcast_i(pk, k);
                float wk = bcast_f(p, k);
                float tq = __half2float(ent16_cur[((pkk & 0x3FFFF) << 6) + lane]);
                int ja = base + k;
                if (ja >= rend) {
                    acc = fmaf(wv, racc, acc); racc = 0.f;
                    do { ++r_cur; rend = startp[r_cur + 1]; } while (ja >= rend);
                    wv = wt[(r_cur << 6) + lane];
                }
                racc = fmaf(wk, tq, racc);
            }
        }
        acc = fmaf(wv, racc, acc);             // final run flush
        float agg = (l > 0.f) ? acc / l : 0.f;

        // --- + interact_mat^T @ user_emb  (nnz with col == e) ---
        int c1 = min(start[E9OFF + e + 1] - NE, NNZV);
        int c0 = max(min(start[E9OFF + e] - NE, c1), 0);
        for (int base = c0; base < c1; base += 64) {
            int j = base + lane;
            int cnt = min(64, c1 - base);
            int rr = 0; float vv = 0.f;
            if (j < c1) { int2 q = rc[j]; rr = q.x; vv = __int_as_float(q.y); }
            int k = 0;
            for (; k + 4 <= cnt; k += 4) {
#pragma unroll
                for (int q = 0; q < 4; ++q) {
                    int u = bcast_i(rr, k + q);
                    float v = bcast_f(vv, k + q);
                    agg += v * __half2float(usr16_cur[(u << 6) + lane]);
                }
            }
            for (; k < cnt; ++k) {
                int u = bcast_i(rr, k);
                float v = bcast_f(vv, k);
                agg += v * __half2float(usr16_cur[(u << 6) + lane]);
            }
        }

        // --- normalize + residual (+ next-hop sq from registers) ---
        float s = wave_sum(agg * agg);
        float y = agg / fmaxf(sqrtf(s), 1e-12f);
        int oi = (e << 6) + lane;
        if (!LAST) {
            ent16_next[oi] = __float2half(y);
            float y2 = y * y;
            float mine = 0.f;
#pragma unroll
            for (int rt = 0; rt < NREL9; ++rt) {
                float r = wt[(rt << 6) + lane];
                float sv = wave_sum(y2 * r * r);
                if (lane == rt) mine = sv;
            }
            if (lane < NREL9) sq_out[e * NREL9 + lane] = mine;
        }
        if (FIRST) out_ent[oi] = ent_res_base[oi] + y;
        else       out_ent[oi] += y;
    } else {
        // ================= user role: one wave per user ==================
        int u = ((b - EG) * 256 + (int)threadIdx.x) >> 6;
        int s1 = min(start[E9OFF + N_ENT + u + 1] - 2 * NE, NNZV);
        int s0 = max(min(start[E9OFF + N_ENT + u] - 2 * NE, s1), 0);
        float acc = 0.f;
        for (int base = s0; base < s1; base += 64) {
            int j = base + lane;
            int cnt = min(64, s1 - base);
            int cc = 0; float vv = 0.f;
            if (j < s1) { int2 q = cv[j]; cc = q.x; vv = __int_as_float(q.y); }
            int k = 0;
            for (; k + 4 <= cnt; k += 4) {
#pragma unroll
                for (int q = 0; q < 4; ++q) {
                    int c = bcast_i(cc, k + q);
                    float v = bcast_f(vv, k + q);
                    acc += v * __half2float(ent16_cur[(c << 6) + lane]);
                }
            }
            for (; k < cnt; ++k) {
                int c = bcast_i(cc, k);
                float v = bcast_f(vv, k);
                acc += v * __half2float(ent16_cur[(c << 6) + lane]);
            }
        }
        float s = wave_sum(acc * acc);
        float y = acc / fmaxf(sqrtf(s), 1e-12f);
        int oi = (u << 6) + lane;
        if (!LAST) usr16_next[oi] = __float2half(y);
        if (FIRST) out_usr[oi] = usr_res_base[oi] + y;
        else       out_usr[oi] += y;
    }
}

extern "C" void kernel_launch(void* const* d_in, const int* in_sizes, int n_in,
                              void* d_out, int out_size, void* d_ws, size_t ws_size,
                              hipStream_t stream)
{
    const float* user_emb   = (const float*)d_in[0];
    const float* entity_emb = (const float*)d_in[1];
    const float* wt         = (const float*)d_in[2];
    const float* inter_vals = (const float*)d_in[3];
    const int*   edge_index = (const int*)d_in[4];
    const int*   etype      = (const int*)d_in[5];
    const int*   inter_rows = (const int*)d_in[6];
    const int*   inter_cols = (const int*)d_in[7];
    const int* head  = edge_index;
    const int* tailp = edge_index + NE;

    // ---- Workspace layout (~91 MB) with dead-buffer aliasing ----
    char* w = (char*)d_ws;
    __half* ent16_a = (__half*)w;                      w += (size_t)N_ENT * CDIM * 2;
    __half* ent16_b = (__half*)w;                      w += (size_t)N_ENT * CDIM * 2;
    __half* usr16_a = (__half*)w;                      w += (size_t)N_USR * CDIM * 2;
    __half* usr16_b = (__half*)w;                      w += (size_t)N_USR * CDIM * 2;
    int2*  rc    = (int2*)w;                           w += (size_t)NNZV * 8;
    int2*  cv    = (int2*)w;                           w += (size_t)NNZV * 8;
    int*   pk_h  = (int*)w;                            w += (size_t)NE * 4;
    int*   start = (int*)w;                            w += (size_t)(NTOT2 + 2) * 4;
    int*   bsum  = (int*)w;                            w += (size_t)SCAN_B2 * 4;
    float* sq_a  = (float*)w;                          w += (size_t)N_ENT * NREL9 * 4;
    float* sq_b  = (float*)w;                          w += (size_t)N_ENT * NREL9 * 4;
    // Aliases over dead regions:
    //  cnt (6.24MB) over sq_a+sq_b (10.8MB): cnt dead after k_scan_apply,
    //    sq_a written by k_prep_ent AFTER that; sq_b written in hop 1.
    //  cursor (6.24MB) over ent16_b (19.2MB): cursor dead after k_scatter,
    //    ent16_b written by hop 1 AFTER that.
    int* cnt    = (int*)sq_a;
    int* cursor = (int*)ent16_b;

    float* out_ent = (float*)d_out;
    float* out_usr = out_ent + (size_t)N_ENT * CDIM;

    // ---- CSR build with per-(head,rt) entity counters ----
    k_zero<<<(NTOT2 + 255) / 256, 256, 0, stream>>>(cnt, NTOT2);
    k_hist<<<(NE + 255) / 256, 256, 0, stream>>>(head, etype, inter_cols, inter_rows, cnt);
    k_bsum<<<SCAN_B2, 1024, 0, stream>>>(cnt, bsum);
    k_scan_small<<<1, 1024, 0, stream>>>(bsum);
    k_scan_apply<<<SCAN_B2, 1024, 0, stream>>>(cnt, bsum, start, cursor);
    k_scatter<<<NCHUNK * NXCD, 256, 0, stream>>>(
        head, tailp, etype, inter_rows, inter_cols, inter_vals,
        cursor, pk_h, rc, cv);

    // ---- hop-1 prep: fp16 tables + sq_a (one pass over entity_emb) ----
    k_prep_ent<<<EG, 256, 0, stream>>>(entity_emb, wt, ent16_a, sq_a);
    {
        int n2u = N_USR * CDIM / 2;
        k_cvt<<<(n2u + 255) / 256, 256, 0, stream>>>(user_emb, usr16_a, n2u);
    }

    // ---- hop 1: gather fp16_a; write fp16_b + sq_b; out = input + y1 ----
    k_hop<true, false><<<EG + UG, 256, 0, stream>>>(
        ent16_a, usr16_a, entity_emb, user_emb, wt, start, pk_h, sq_a, rc, cv,
        ent16_b, usr16_b, sq_b, out_ent, out_usr);

    // ---- hop 2: gather fp16_b; out += y2 ----
    k_hop<false, true><<<EG + UG, 256, 0, stream>>>(
        ent16_b, usr16_b, nullptr, nullptr, wt, start, pk_h, sq_b, rc, cv,
        nullptr, nullptr, nullptr, out_ent, out_usr);
}

// Round 7
// 700.837 us; speedup vs baseline: 1.1425x; 1.1425x over previous
//
#include <hip/hip_runtime.h>
#include <hip/hip_fp16.h>
#include <math.h>

#define N_ENT  150000
#define N_USR  60000
#define CDIM   64
#define NE     1000000
#define NNZV   1000000
#define NREL9  9                        // weight rows incl. np-wrap row 8
#define NTOT   (2 * N_ENT + N_USR)      // 360000 concatenated segment counters
#define TOTAL_ITEMS (NE + 2 * NNZV)     // 3000000 (scan sentinel)
#define SCAN_B ((NTOT + 1023) / 1024)   // 352 scan blocks

#define NXCD   8
#define H_PER  (N_ENT / NXCD)           // 18750 heads/cols per role
#define R_PER  (N_USR / NXCD)           // 7500 rows per role
#define EPB    2048                     // edges per chunk
#define NCHUNK ((NE + EPB - 1) / EPB)   // 489

#define EG (N_ENT / 4)                  // 37500 entity blocks (4 waves each)
#define UG (N_USR / 4)                  // 15000 user blocks
#define UCVT ((N_USR * CDIM / 2 + 255) / 256)  // 7500 usr-cvt blocks in k_prep

// ---- DPP wave reductions (VALU pipe, no LDS) ----------------------------
// rocPRIM warp_reduce_dpp pattern. bound_ctrl=true: OOR lanes contribute 0 —
// exact for sum, and for max of non-negative values.
template <int CTRL>
__device__ __forceinline__ float dpp_addf(float v) {
    int iv = __float_as_int(v);
    int x = __builtin_amdgcn_update_dpp(iv, iv, CTRL, 0xF, 0xF, true);
    return v + __int_as_float(x);
}
template <int CTRL>
__device__ __forceinline__ float dpp_maxf(float v) {
    int iv = __float_as_int(v);
    int x = __builtin_amdgcn_update_dpp(iv, iv, CTRL, 0xF, 0xF, true);
    return fmaxf(v, __int_as_float(x));
}
__device__ __forceinline__ float wave_sum(float v) {
    v = dpp_addf<0x111>(v);   // row_shr:1
    v = dpp_addf<0x112>(v);   // row_shr:2
    v = dpp_addf<0x114>(v);   // row_shr:4
    v = dpp_addf<0x118>(v);   // row_shr:8
    v = dpp_addf<0x142>(v);   // row_bcast:15
    v = dpp_addf<0x143>(v);   // row_bcast:31
    return __int_as_float(__builtin_amdgcn_readlane(__float_as_int(v), 63));
}
__device__ __forceinline__ float wave_max(float v) {
    v = dpp_maxf<0x111>(v);
    v = dpp_maxf<0x112>(v);
    v = dpp_maxf<0x114>(v);
    v = dpp_maxf<0x118>(v);
    v = dpp_maxf<0x142>(v);
    v = dpp_maxf<0x143>(v);
    return __int_as_float(__builtin_amdgcn_readlane(__float_as_int(v), 63));
}

// Uniform-lane broadcast: readlane result is uniform to the compiler, so
// pointers derived from it become SGPR bases (saddr loads, SALU addr math).
__device__ __forceinline__ int   bcast_i(int v, int l)   { return __builtin_amdgcn_readlane(v, l); }
__device__ __forceinline__ float bcast_f(float v, int l) { return __int_as_float(__builtin_amdgcn_readlane(__float_as_int(v), l)); }

// Block-wide exclusive scan (blockDim multiple of 64, <=1024). lds: >=16 ints.
__device__ __forceinline__ int block_excl_scan(int v, int* lds) {
    int lane = threadIdx.x & 63, wid = threadIdx.x >> 6;
    int incl = v;
#pragma unroll
    for (int o = 1; o < 64; o <<= 1) {
        int t = __shfl_up(incl, o, 64);
        if (lane >= o) incl += t;
    }
    if (lane == 63) lds[wid] = incl;
    __syncthreads();
    int nw = blockDim.x >> 6;
    if ((int)threadIdx.x < nw) {
        int s = lds[threadIdx.x];
        int si = s;
        for (int o = 1; o < nw; o <<= 1) {
            int t = __shfl_up(si, o, 64);
            if ((int)threadIdx.x >= o) si += t;
        }
        lds[threadIdx.x] = si - s;  // exclusive offset for this wave
    }
    __syncthreads();
    return incl - v + lds[wid];
}

__global__ __launch_bounds__(256) void k_zero(int* __restrict__ p, int n) {
    int i = blockIdx.x * 256 + threadIdx.x;
    if (i < n) p[i] = 0;
}

// ---- CSR build: histogram -> scan(start,cursor) -> scatter ---------------

// Role-split histogram (XCD-localized atomics, same trick as k_scatter R0):
// role r only increments counters in its eighth of segment space, so each
// counter's atomics stay within one XCD's L2. Edge keys re-read 8x (L2/L3).
__global__ __launch_bounds__(256) void k_hist(
    const int* __restrict__ head, const int* __restrict__ cols,
    const int* __restrict__ rows, int* __restrict__ cnt)
{
    int role  = blockIdx.x & (NXCD - 1);
    int chunk = blockIdx.x >> 3;
    int h0 = role * H_PER, h1 = h0 + H_PER;
    int r0 = role * R_PER, r1 = r0 + R_PER;
    int base = chunk * EPB;
    int end  = min(base + EPB, NE);
    for (int i = base + (int)threadIdx.x; i < end; i += 256) {
        int h = head[i];
        int c = cols[i];
        int r = rows[i];
        if (h >= h0 && h < h1) atomicAdd(cnt + h, 1);
        if (c >= h0 && c < h1) atomicAdd(cnt + N_ENT + c, 1);
        if (r >= r0 && r < r1) atomicAdd(cnt + 2 * N_ENT + r, 1);
    }
}

__global__ __launch_bounds__(1024) void k_bsum(
    const int* __restrict__ cnt, int* __restrict__ bsum)
{
    __shared__ int lds[16];
    int i = blockIdx.x * 1024 + threadIdx.x;
    float v = (i < NTOT) ? (float)cnt[i] : 0.f;
    float s = wave_sum(v);                 // exact: block total <= 3M < 2^24
    int lane = threadIdx.x & 63, wid = threadIdx.x >> 6;
    if (lane == 0) lds[wid] = (int)s;
    __syncthreads();
    if (threadIdx.x == 0) {
        int t = 0;
        for (int k = 0; k < 16; ++k) t += lds[k];
        bsum[blockIdx.x] = t;
    }
}

__global__ __launch_bounds__(512) void k_scan_small(int* __restrict__ bsum)
{
    __shared__ int lds[16];
    int i = threadIdx.x;
    int v = (i < SCAN_B) ? bsum[i] : 0;
    int e = block_excl_scan(v, lds);
    if (i < SCAN_B) bsum[i] = e;
}

// start[i] = exclusive prefix (immutable); start[NTOT] = sentinel.
__global__ __launch_bounds__(1024) void k_scan_apply(
    const int* __restrict__ cnt, const int* __restrict__ bsum,
    int* __restrict__ start, int* __restrict__ cursor)
{
    __shared__ int lds[16];
    int i = blockIdx.x * 1024 + threadIdx.x;
    int v = (i < NTOT) ? cnt[i] : 0;
    int e = block_excl_scan(v, lds) + bsum[blockIdx.x];
    if (i < NTOT) { start[i] = e; cursor[i] = e; }
    else if (i == NTOT) { start[i] = TOTAL_ITEMS; }
}

// Scatter payloads into segment-sorted arrays. XCD-localized (R0). Payload
// fields loaded CONDITIONALLY: tail/etype only when head in range (1/8),
// vals only when col/row in range — cuts role read traffic ~45%.
__global__ __launch_bounds__(256) void k_scatter(
    const int* __restrict__ head, const int* __restrict__ tail,
    const int* __restrict__ etype,
    const int* __restrict__ rows, const int* __restrict__ cols,
    const float* __restrict__ vals,
    int* __restrict__ cursor,
    int* __restrict__ pk_h,                  // tail | rt<<18, sorted by head
    int2* __restrict__ rc,                   // (row, valbits) sorted by col
    int2* __restrict__ cv)                   // (col, valbits) sorted by row
{
    int role  = blockIdx.x & (NXCD - 1);
    int chunk = blockIdx.x >> 3;
    int h0 = role * H_PER, h1 = h0 + H_PER;
    int r0 = role * R_PER, r1 = r0 + R_PER;
    int base = chunk * EPB;
    int end  = min(base + EPB, NE);
    for (int i = base + (int)threadIdx.x; i < end; i += 256) {
        int h = head[i];
        int c = cols[i];
        int r = rows[i];
        if (h >= h0 && h < h1) {
            int rt = etype[i] - 1;
            if (rt < 0) rt = 8;              // weight[-1] -> row 8 (np wrap)
            int p = atomicAdd(cursor + h, 1);
            if ((unsigned)p < (unsigned)NE) pk_h[p] = tail[i] | (rt << 18);
        }
        if (c >= h0 && c < h1) {
            int vb = __float_as_int(vals[i]);
            int p = atomicAdd(cursor + N_ENT + c, 1) - NE;
            if ((unsigned)p < (unsigned)NNZV) rc[p] = make_int2(r, vb);
        }
        if (r >= r0 && r < r1) {
            int vb = __float_as_int(vals[i]);
            int p = atomicAdd(cursor + 2 * N_ENT + r, 1) - 2 * NE;
            if ((unsigned)p < (unsigned)NNZV) cv[p] = make_int2(c, vb);
        }
    }
}

// ---- Fused hop-1 prep: blocks [0,EG) entity cvt + sq; rest usr cvt. -----
__global__ __launch_bounds__(256) void k_prep(
    const float* __restrict__ ent, const float* __restrict__ usr,
    const float* __restrict__ wt,
    __half* __restrict__ ent16, __half* __restrict__ usr16,
    float* __restrict__ sq)
{
    int b = blockIdx.x;
    if (b < EG) {
        int e = (b * 256 + (int)threadIdx.x) >> 6;
        int lane = threadIdx.x & 63;
        float own = ent[(e << 6) + lane];
        ent16[(e << 6) + lane] = __float2half(own);
        float o2 = own * own;
        float mine = 0.f;
#pragma unroll
        for (int rt = 0; rt < NREL9; ++rt) {
            float r = wt[(rt << 6) + lane];
            float s = wave_sum(o2 * r * r);
            if (lane == rt) mine = s;
        }
        if (lane < NREL9) sq[e * NREL9 + lane] = mine;
    } else {
        int i = (b - EG) * 256 + (int)threadIdx.x;   // float2 index
        if (i < N_USR * CDIM / 2) {
            float2 v = ((const float2*)usr)[i];
            ((__half2*)usr16)[i] = __floats2half2_rn(v.x, v.y);
        }
    }
}

// ---- Fused per-hop kernel: blocks [0,EG) = entity role, rest = user. ----
// (Exact R5 structure: fp16 gather tables, 4-deep batched gathers, DPP
// online softmax. No per-edge control flow in the inner loop.)
template <bool FIRST, bool LAST>
__global__ __launch_bounds__(256) void k_hop(
    const __half* __restrict__ ent16_cur, const __half* __restrict__ usr16_cur,
    const float* __restrict__ ent_res_base, const float* __restrict__ usr_res_base,
    const float* __restrict__ wt, const int* __restrict__ start,
    const int* __restrict__ pk_h, const float* __restrict__ sq_in,
    const int2* __restrict__ rc, const int2* __restrict__ cv,
    __half* __restrict__ ent16_next, __half* __restrict__ usr16_next,
    float* __restrict__ sq_out,
    float* __restrict__ out_ent, float* __restrict__ out_usr)
{
    int lane = threadIdx.x & 63;
    int b = blockIdx.x;

    if (b < EG) {
        // ================= entity role: one wave per entity ==============
        int e = (b * 256 + (int)threadIdx.x) >> 6;

        // --- softmax-weighted neighbor aggregation, edges head == e ---
        int s1 = min(start[e + 1], NE);
        int s0 = min(start[e], s1);
        float m = 0.f, l = 0.f, acc = 0.f;    // att >= 0 so m=0 init exact
        for (int base = s0; base < s1; base += 64) {
            int j = base + lane;
            int cnt = min(64, s1 - base);
            int pk = 0; float att = 0.f;
            if (j < s1) {                      // coalesced descriptor load
                pk = pk_h[j];
                int t = pk & 0x3FFFF, rt = (pk >> 18) & 15;
                att = sq_in[e * NREL9 + rt] * sq_in[t * NREL9 + rt];
            }
            float mn = fmaxf(m, wave_max(att));
            float scale = __expf(m - mn);      // first chunk multiplies zeros
            float p = (j < s1) ? __expf(att - mn) : 0.f;
            l = l * scale + wave_sum(p);
            acc *= scale;
            m = mn;
            int k = 0;
            for (; k + 4 <= cnt; k += 4) {     // 4 independent gathers in flight
#pragma unroll
                for (int q = 0; q < 4; ++q) {
                    int pkk = bcast_i(pk, k + q);
                    float wk = bcast_f(p, k + q);
                    const __half* tp = ent16_cur + ((pkk & 0x3FFFF) << 6);
                    const float*  wp = wt + (((pkk >> 18) & 15) << 6);
                    acc += wk * __half2float(tp[lane]) * wp[lane];
                }
            }
            for (; k < cnt; ++k) {
                int pkk = bcast_i(pk, k);
                float wk = bcast_f(p, k);
                const __half* tp = ent16_cur + ((pkk & 0x3FFFF) << 6);
                const float*  wp = wt + (((pkk >> 18) & 15) << 6);
                acc += wk * __half2float(tp[lane]) * wp[lane];
            }
        }
        float agg = (l > 0.f) ? acc / l : 0.f;

        // --- + interact_mat^T @ user_emb  (nnz with col == e) ---
        int c1 = min(start[N_ENT + e + 1] - NE, NNZV);
        int c0 = max(min(start[N_ENT + e] - NE, c1), 0);
        for (int base = c0; base < c1; base += 64) {
            int j = base + lane;
            int cnt = min(64, c1 - base);
            int rr = 0; float vv = 0.f;
            if (j < c1) { int2 q = rc[j]; rr = q.x; vv = __int_as_float(q.y); }
            int k = 0;
            for (; k + 4 <= cnt; k += 4) {
#pragma unroll
                for (int q = 0; q < 4; ++q) {
                    int u = bcast_i(rr, k + q);
                    float v = bcast_f(vv, k + q);
                    agg += v * __half2float(usr16_cur[(u << 6) + lane]);
                }
            }
            for (; k < cnt; ++k) {
                int u = bcast_i(rr, k);
                float v = bcast_f(vv, k);
                agg += v * __half2float(usr16_cur[(u << 6) + lane]);
            }
        }

        // --- normalize + residual (+ next-hop sq from registers) ---
        float s = wave_sum(agg * agg);
        float y = agg / fmaxf(sqrtf(s), 1e-12f);
        int oi = (e << 6) + lane;
        if (!LAST) {
            ent16_next[oi] = __float2half(y);
            float y2 = y * y;
            float mine = 0.f;
#pragma unroll
            for (int rt = 0; rt < NREL9; ++rt) {
                float r = wt[(rt << 6) + lane];
                float sv = wave_sum(y2 * r * r);
                if (lane == rt) mine = sv;
            }
            if (lane < NREL9) sq_out[e * NREL9 + lane] = mine;
        }
        if (FIRST) out_ent[oi] = ent_res_base[oi] + y;
        else       out_ent[oi] += y;
    } else {
        // ================= user role: one wave per user ==================
        int u = ((b - EG) * 256 + (int)threadIdx.x) >> 6;
        int s1 = min(start[2 * N_ENT + u + 1] - 2 * NE, NNZV);
        int s0 = max(min(start[2 * N_ENT + u] - 2 * NE, s1), 0);
        float acc = 0.f;
        for (int base = s0; base < s1; base += 64) {
            int j = base + lane;
            int cnt = min(64, s1 - base);
            int cc = 0; float vv = 0.f;
            if (j < s1) { int2 q = cv[j]; cc = q.x; vv = __int_as_float(q.y); }
            int k = 0;
            for (; k + 4 <= cnt; k += 4) {
#pragma unroll
                for (int q = 0; q < 4; ++q) {
                    int c = bcast_i(cc, k + q);
                    float v = bcast_f(vv, k + q);
                    acc += v * __half2float(ent16_cur[(c << 6) + lane]);
                }
            }
            for (; k < cnt; ++k) {
                int c = bcast_i(cc, k);
                float v = bcast_f(vv, k);
                acc += v * __half2float(ent16_cur[(c << 6) + lane]);
            }
        }
        float s = wave_sum(acc * acc);
        float y = acc / fmaxf(sqrtf(s), 1e-12f);
        int oi = (u << 6) + lane;
        if (!LAST) usr16_next[oi] = __float2half(y);
        if (FIRST) out_usr[oi] = usr_res_base[oi] + y;
        else       out_usr[oi] += y;
    }
}

extern "C" void kernel_launch(void* const* d_in, const int* in_sizes, int n_in,
                              void* d_out, int out_size, void* d_ws, size_t ws_size,
                              hipStream_t stream)
{
    const float* user_emb   = (const float*)d_in[0];
    const float* entity_emb = (const float*)d_in[1];
    const float* wt         = (const float*)d_in[2];
    const float* inter_vals = (const float*)d_in[3];
    const int*   edge_index = (const int*)d_in[4];
    const int*   etype      = (const int*)d_in[5];
    const int*   inter_rows = (const int*)d_in[6];
    const int*   inter_cols = (const int*)d_in[7];
    const int* head  = edge_index;
    const int* tailp = edge_index + NE;

    // Workspace layout (~89 MB); every buffer written before read each call.
    __half* ent16_a = (__half*)d_ws;                         // N_ENT*64 halves
    __half* ent16_b = ent16_a + (size_t)N_ENT * CDIM;        // N_ENT*64
    __half* usr16_a = ent16_b + (size_t)N_ENT * CDIM;        // N_USR*64
    __half* usr16_b = usr16_a + (size_t)N_USR * CDIM;        // N_USR*64
    int2*  rc     = (int2*)(usr16_b + (size_t)N_USR * CDIM); // NNZ
    int2*  cv     = rc + NNZV;                               // NNZ
    int*   pk_h   = (int*)(cv + NNZV);                       // NE
    int*   cnt    = pk_h + NE;                               // NTOT
    int*   start  = cnt + NTOT;                              // NTOT+1
    int*   cursor = start + NTOT + 1;                        // NTOT+1
    int*   bsum   = cursor + NTOT + 1;                       // SCAN_B
    float* sq_a   = (float*)(bsum + SCAN_B);                 // N_ENT*9
    float* sq_b   = sq_a + (size_t)N_ENT * NREL9;            // N_ENT*9

    float* out_ent = (float*)d_out;
    float* out_usr = out_ent + (size_t)N_ENT * CDIM;

    // ---- CSR build (indices are hop-invariant: once per call) ----
    k_zero<<<(NTOT + 255) / 256, 256, 0, stream>>>(cnt, NTOT);
    k_hist<<<NCHUNK * NXCD, 256, 0, stream>>>(head, inter_cols, inter_rows, cnt);
    k_bsum<<<SCAN_B, 1024, 0, stream>>>(cnt, bsum);
    k_scan_small<<<1, 512, 0, stream>>>(bsum);
    k_scan_apply<<<SCAN_B, 1024, 0, stream>>>(cnt, bsum, start, cursor);
    k_scatter<<<NCHUNK * NXCD, 256, 0, stream>>>(
        head, tailp, etype, inter_rows, inter_cols, inter_vals,
        cursor, pk_h, rc, cv);

    // ---- hop-1 prep: ent fp16 + sq_a + usr fp16 in ONE kernel ----
    k_prep<<<EG + UCVT, 256, 0, stream>>>(
        entity_emb, user_emb, wt, ent16_a, usr16_a, sq_a);

    // ---- hop 1: gather fp16_a; write fp16_b + sq_b; out = input + y1 ----
    k_hop<true, false><<<EG + UG, 256, 0, stream>>>(
        ent16_a, usr16_a, entity_emb, user_emb, wt, start, pk_h, sq_a, rc, cv,
        ent16_b, usr16_b, sq_b, out_ent, out_usr);

    // ---- hop 2: gather fp16_b; out += y2 ----
    k_hop<false, true><<<EG + UG, 256, 0, stream>>>(
        ent16_b, usr16_b, nullptr, nullptr, wt, start, pk_h, sq_b, rc, cv,
        nullptr, nullptr, nullptr, out_ent, out_usr);
}